// Round 11
// baseline (174.414 us; speedup 1.0000x reference)
//
#include <hip/hip_runtime.h>

// GraphConv (DGL norm='both', implicit self-loop), N=100000, D=64, E=1250000.
// R10: R9's fused sortgather lost wave-level MLP (16 nodes serial per wave,
// 8 loads in flight) vs the R8 standalone gather. Fix: 2-node software
// pipeline - each wave gathers node pair (r, r+16) with 16 independent 128B
// featb loads in flight before any accumulate-wait. Partition EPB 8192->4096
// (306 blocks, 2x waves/CU) for its latency-bound LDS-atomic/store chains.
// Pipeline: memset(3KB) -> partition -> convertB -> sortgather.

#define GC_D 64
#define PBITS 8
#define PSIZE 256     // nodes per partition
#define SCAP 4096     // stream slots per partition (mean 3197, +16 sigma)
#define EPB 4096      // edges per block in partition pass
#define MAXPART 512
#define GC_CAP 64     // fallback-A bucket capacity

// ---------------- main-path kernels ----------------

__global__ __launch_bounds__(512) void partition_kernel(
        const int* __restrict__ src,
        const int* __restrict__ dst,
        int* __restrict__ curA,                 // [nPart] cursors (dst-keyed)
        int* __restrict__ curB,                 // [nPart] cursors (src-keyed)
        int* __restrict__ streamA,              // [nPart*SCAP] s | (d&255)<<17
        unsigned char* __restrict__ streamB,    // [nPart*SCAP] s&255
        int e, int nPart) {
    __shared__ int histA[MAXPART], histB[MAXPART], baseA[MAXPART], baseB[MAXPART];
    __shared__ int lcurA[MAXPART], lcurB[MAXPART];
    int t = threadIdx.x;
    for (int i = t; i < nPart; i += 512) {
        histA[i] = 0; histB[i] = 0; lcurA[i] = 0; lcurB[i] = 0;
    }
    __syncthreads();
    int lo = blockIdx.x * EPB;
    int hi = min(lo + EPB, e);
    for (int i = lo + t; i < hi; i += 512) {
        int s = src[i], d = dst[i];
        atomicAdd(&histA[d >> PBITS], 1);
        atomicAdd(&histB[s >> PBITS], 1);
    }
    __syncthreads();
    for (int i = t; i < nPart; i += 512) {
        int hA = histA[i];
        baseA[i] = hA ? atomicAdd(&curA[i], hA) : 0;
        int hB = histB[i];
        baseB[i] = hB ? atomicAdd(&curB[i], hB) : 0;
    }
    __syncthreads();
    for (int i = lo + t; i < hi; i += 512) {
        int s = src[i], d = dst[i];
        int pA = d >> PBITS;
        int posA = baseA[pA] + atomicAdd(&lcurA[pA], 1);
        if (posA < SCAP) streamA[pA * SCAP + posA] = s | ((d & 255) << 17);
        int pB = s >> PBITS;
        int posB = baseB[pB] + atomicAdd(&lcurB[pB], 1);
        if (posB < SCAP) streamB[pB * SCAP + posB] = (unsigned char)(s & 255);
    }
}

// One block per partition: outdeg hist from streamB, then premultiplied bf16
// convert of this partition's 256 rows. featb row n = zeros (pad target).
__global__ __launch_bounds__(512) void convertB_kernel(
        const int* __restrict__ curB,
        const unsigned char* __restrict__ streamB,
        const float* __restrict__ feat,
        unsigned short* __restrict__ featb,
        int n) {
    __shared__ int lodeg[PSIZE];
    int p = blockIdx.x, t = threadIdx.x;
    if (t < PSIZE) lodeg[t] = 0;
    __syncthreads();
    int cB = min(curB[p], SCAP);
    const unsigned char* sB = streamB + (size_t)p * SCAP;
    for (int i = t; i < cB; i += 512) atomicAdd(&lodeg[sB[i]], 1);
    __syncthreads();
    int wave = t >> 6, lane = t & 63;
    int g = p * PSIZE;
    for (int r = wave; r < PSIZE; r += 8) {
        int node = g + r;
        if (node >= n) break;
        float nl = rsqrtf(fmaxf((float)lodeg[r], 1.0f) + 1.0f);
        float v = feat[(size_t)node * GC_D + lane] * nl;
        unsigned bb = __float_as_uint(v);
        bb = (bb + 0x7FFFu + ((bb >> 16) & 1u)) >> 16;   // RNE to bf16
        featb[(size_t)node * GC_D + lane] = (unsigned short)bb;
    }
    if (p == 0 && t < GC_D) featb[(size_t)n * GC_D + t] = 0;
}

// One 1024-thread block per partition. Drain streamA into LDS, LDS counting
// sort into lperm, then 16 waves gather 2 nodes at a time (r, r+16) with 16
// independent featb loads in flight per wave.
__global__ __launch_bounds__(1024) void sortgather_kernel(
        const int* __restrict__ curA,
        const int* __restrict__ streamA,
        const float* __restrict__ feat,
        const unsigned short* __restrict__ featb,
        float* __restrict__ out,
        int n) {
    __shared__ int sAl[SCAP];       // 16 KB staged stream
    __shared__ int lperm[SCAP];     // 16 KB sorted src ids
    __shared__ int lcnt[PSIZE], loff[PSIZE], lcur[PSIZE];
    int p = blockIdx.x, t = threadIdx.x;
    if (t < PSIZE) lcnt[t] = 0;
    __syncthreads();
    int cA = min(curA[p], SCAP);
    const int* sA = streamA + (size_t)p * SCAP;
    for (int i = t; i < cA; i += 1024) {
        int v = sA[i];
        sAl[i] = v;
        atomicAdd(&lcnt[(v >> 17) & 255], 1);
    }
    __syncthreads();
    // exclusive scan of the 256 bins (Hillis-Steele on first 256 threads)
    if (t < PSIZE) loff[t] = lcnt[t];
    __syncthreads();
    for (int off = 1; off < PSIZE; off <<= 1) {
        int a = (t < PSIZE && t >= off) ? loff[t - off] : 0;
        __syncthreads();
        if (t < PSIZE) loff[t] += a;
        __syncthreads();
    }
    if (t < PSIZE) { loff[t] -= lcnt[t]; lcur[t] = 0; }   // exclusive
    __syncthreads();
    for (int i = t; i < cA; i += 1024) {
        int v = sAl[i];
        int bin = (v >> 17) & 255;
        int pos = loff[bin] + atomicAdd(&lcur[bin], 1);
        lperm[pos] = v & 0x1FFFF;
    }
    __syncthreads();
    // gather: wave w handles node pairs (w, w+16), (w+32, w+48), ...
    int wave = t >> 6, lane = t & 63;
    int half = lane >> 5;      // 0: even edges, 1: odd edges
    int c = lane & 31;         // feature-pair index
    int g = p * PSIZE;
    for (int rr = wave; rr < PSIZE; rr += 32) {
        int rA = rr, rB = rr + 16;
        int nodeA = g + rA, nodeB = g + rB;
        int degA = lcnt[rA], degB = lcnt[rB];
        int offA = loff[rA], offB = loff[rB];
        int mA = min(degA, 64), mB = min(degB, 64);
        int s_lA = (lane < mA) ? lperm[offA + lane] : n;
        int s_lB = (lane < mB) ? lperm[offB + lane] : n;
        float a0 = 0.f, a1 = 0.f, b0 = 0.f, b1 = 0.f;
        int mA16 = (mA + 15) & ~15, mB16 = (mB + 15) & ~15;
        int mx = mA16 > mB16 ? mA16 : mB16;
        for (int j = 0; j < mx; j += 16) {
            unsigned uA[8], uB[8];
#pragma unroll
            for (int k = 0; k < 8; ++k) {
                int s = __shfl(s_lA, j + 2 * k + half);
                uA[k] = *(const unsigned*)(featb + (size_t)s * GC_D + 2 * c);
            }
#pragma unroll
            for (int k = 0; k < 8; ++k) {
                int s = __shfl(s_lB, j + 2 * k + half);
                uB[k] = *(const unsigned*)(featb + (size_t)s * GC_D + 2 * c);
            }
#pragma unroll
            for (int k = 0; k < 8; ++k) {
                a0 += __uint_as_float(uA[k] << 16);
                a1 += __uint_as_float(uA[k] & 0xFFFF0000u);
            }
#pragma unroll
            for (int k = 0; k < 8; ++k) {
                b0 += __uint_as_float(uB[k] << 16);
                b1 += __uint_as_float(uB[k] & 0xFFFF0000u);
            }
        }
        // rare tails (deg > 64): sequential batches, statistically ~never
        for (int base = 64; base < degA; base += 64) {
            int m = min(degA - base, 64);
            int s_l = (lane < m) ? lperm[offA + base + lane] : n;
            int m16 = (m + 15) & ~15;
            for (int j = 0; j < m16; j += 16) {
#pragma unroll
                for (int k = 0; k < 8; ++k) {
                    int s = __shfl(s_l, j + 2 * k + half);
                    unsigned u = *(const unsigned*)(featb + (size_t)s * GC_D + 2 * c);
                    a0 += __uint_as_float(u << 16);
                    a1 += __uint_as_float(u & 0xFFFF0000u);
                }
            }
        }
        for (int base = 64; base < degB; base += 64) {
            int m = min(degB - base, 64);
            int s_l = (lane < m) ? lperm[offB + base + lane] : n;
            int m16 = (m + 15) & ~15;
            for (int j = 0; j < m16; j += 16) {
#pragma unroll
                for (int k = 0; k < 8; ++k) {
                    int s = __shfl(s_l, j + 2 * k + half);
                    unsigned u = *(const unsigned*)(featb + (size_t)s * GC_D + 2 * c);
                    b0 += __uint_as_float(u << 16);
                    b1 += __uint_as_float(u & 0xFFFF0000u);
                }
            }
        }
        a0 += __shfl_xor(a0, 32);
        a1 += __shfl_xor(a1, 32);
        b0 += __shfl_xor(b0, 32);
        b1 += __shfl_xor(b1, 32);
        if (half == 0) {
            if (nodeA < n) {
                float nr = rsqrtf(fmaxf((float)degA, 1.0f) + 1.0f);
                const float2 self = *(const float2*)(feat + (size_t)nodeA * GC_D + 2 * c);
                float2 rv;
                rv.x = (self.x + a0) * nr;
                rv.y = (self.y + a1) * nr;
                *(float2*)(out + (size_t)nodeA * GC_D + 2 * c) = rv;
            }
            if (nodeB < n) {
                float nr = rsqrtf(fmaxf((float)degB, 1.0f) + 1.0f);
                const float2 self = *(const float2*)(feat + (size_t)nodeB * GC_D + 2 * c);
                float2 rv;
                rv.x = (self.x + b0) * nr;
                rv.y = (self.y + b1) * nr;
                *(float2*)(out + (size_t)nodeB * GC_D + 2 * c) = rv;
            }
        }
    }
}

// ---------------- fallback A (atomic-bucket path, R4-style) ----------------

__global__ void zero_int_kernel(int* __restrict__ p, int n) {
    int i = blockIdx.x * blockDim.x + threadIdx.x;
    if (i < n) p[i] = 0;
}

__global__ void bucket_hist_kernel(const int* __restrict__ src,
                                   const int* __restrict__ dst,
                                   int* __restrict__ cnt,
                                   int* __restrict__ outdeg,
                                   int* __restrict__ bucket,
                                   int e) {
    int i = blockIdx.x * blockDim.x + threadIdx.x;
    if (i < e) {
        int s = src[i];
        int d = dst[i];
        atomicAdd(&outdeg[s], 1);
        int pos = atomicAdd(&cnt[d], 1);
        if (pos < GC_CAP) bucket[d * GC_CAP + pos] = s;
    }
}

__global__ void convert_kernel(const float* __restrict__ feat,
                               const int* __restrict__ outdeg,
                               unsigned short* __restrict__ featb,
                               int n) {
    int i = blockIdx.x * blockDim.x + threadIdx.x;
    int total = (n + 1) * GC_D;
    if (i >= total) return;
    int row = i >> 6;
    if (row >= n) { featb[i] = 0; return; }
    float nl = rsqrtf(fmaxf((float)outdeg[row], 1.0f) + 1.0f);
    unsigned b = __float_as_uint(feat[i] * nl);
    b = (b + 0x7FFFu + ((b >> 16) & 1u)) >> 16;
    featb[i] = (unsigned short)b;
}

__global__ __launch_bounds__(256) void gather_bf16_kernel(
        const float* __restrict__ feat,
        const unsigned short* __restrict__ featb,
        const int* __restrict__ bucket,
        const int* __restrict__ cnt,
        float* __restrict__ out,
        int n) {
    int wid = (blockIdx.x * blockDim.x + threadIdx.x) >> 6;
    int lane = threadIdx.x & 63;
    if (wid >= n) return;
    int deg = cnt[wid];
    int s_raw = bucket[wid * GC_CAP + lane];
    int m = min(deg, GC_CAP);
    int s_l = (lane < m) ? s_raw : n;
    int half = lane >> 5;
    int c = lane & 31;
    float acc0 = 0.0f, acc1 = 0.0f;
    int m16 = (m + 15) & ~15;
    for (int j = 0; j < m16; j += 16) {
#pragma unroll
        for (int k = 0; k < 8; ++k) {
            int s = __shfl(s_l, j + 2 * k + half);
            unsigned u = *(const unsigned*)(featb + (size_t)s * GC_D + 2 * c);
            acc0 += __uint_as_float(u << 16);
            acc1 += __uint_as_float(u & 0xFFFF0000u);
        }
    }
    acc0 += __shfl_xor(acc0, 32);
    acc1 += __shfl_xor(acc1, 32);
    if (half == 0) {
        float nr = rsqrtf(fmaxf((float)deg, 1.0f) + 1.0f);
        const float2 self = *(const float2*)(feat + (size_t)wid * GC_D + 2 * c);
        float2 r;
        r.x = (self.x + acc0) * nr;
        r.y = (self.y + acc1) * nr;
        *(float2*)(out + (size_t)wid * GC_D + 2 * c) = r;
    }
}

// ---------------- launch ----------------

extern "C" void kernel_launch(void* const* d_in, const int* in_sizes, int n_in,
                              void* d_out, int out_size, void* d_ws, size_t ws_size,
                              hipStream_t stream) {
    const float* feat = (const float*)d_in[0];
    const int*   src  = (const int*)d_in[1];
    const int*   dst  = (const int*)d_in[2];
    float* out = (float*)d_out;

    const int n = in_sizes[0] / GC_D;   // 100000
    const int e = in_sizes[1];          // 1250000
    const int nPart = (n + PSIZE - 1) >> PBITS;   // 391

    // Main ws layout (int units): curA[nPart] curB[nPart] pad32 ->
    //   streamA[nPart*SCAP] -> featb[(n+1)*64 u16] -> streamB[nPart*SCAP u8]
    size_t featb_ints = ((size_t)(n + 1) * GC_D + 1) / 2;
    size_t o = 2 * (size_t)nPart;
    o = (o + 31) & ~(size_t)31;          // 128B-align streamA (and featb below)
    size_t streamA_o = o;  o += (size_t)nPart * SCAP;
    size_t featb_o = o;    o += featb_ints;
    size_t need_main = o * sizeof(int) + (size_t)nPart * SCAP;   // + streamB u8

    size_t featb_bytes = (size_t)(n + 1) * GC_D * sizeof(unsigned short);
    size_t need_bf16 = ((size_t)2 * n + (size_t)n * GC_CAP) * sizeof(int) + featb_bytes;

    bool main_ok = (ws_size >= need_main) && nPart <= MAXPART && n <= 131071;

    if (main_ok) {
        int* ws = (int*)d_ws;
        int* curA = ws;
        int* curB = ws + nPart;
        int* streamA = ws + streamA_o;
        unsigned short* featb = (unsigned short*)(ws + featb_o);
        unsigned char* streamB = (unsigned char*)(ws + o);

        hipMemsetAsync(curA, 0, 2 * (size_t)nPart * sizeof(int), stream);
        partition_kernel<<<(e + EPB - 1) / EPB, 512, 0, stream>>>(
            src, dst, curA, curB, streamA, streamB, e, nPart);
        convertB_kernel<<<nPart, 512, 0, stream>>>(curB, streamB, feat, featb, n);
        sortgather_kernel<<<nPart, 1024, 0, stream>>>(curA, streamA, feat, featb,
                                                      out, n);
    } else if (ws_size >= need_bf16) {
        int* cnt    = (int*)d_ws;
        int* outdeg = cnt + n;
        int* bucket = outdeg + n;
        unsigned short* featb = (unsigned short*)(bucket + (size_t)n * GC_CAP);

        zero_int_kernel<<<(2 * n + 255) / 256, 256, 0, stream>>>(cnt, 2 * n);
        bucket_hist_kernel<<<(e + 255) / 256, 256, 0, stream>>>(src, dst, cnt,
                                                                outdeg, bucket, e);
        int totalc = (n + 1) * GC_D;
        convert_kernel<<<(totalc + 255) / 256, 256, 0, stream>>>(feat, outdeg,
                                                                 featb, n);
        long long total = (long long)n * GC_D;
        gather_bf16_kernel<<<(int)((total + 255) / 256), 256, 0, stream>>>(
            feat, featb, bucket, cnt, out, n);
    }
}

// Round 12
// 169.832 us; speedup vs baseline: 1.0270x; 1.0270x over previous
//
#include <hip/hip_runtime.h>

// GraphConv (DGL norm='both', implicit self-loop), N=100000, D=64, E=1250000.
// R11: combine the measured winners. R10's 2-node pipelined sortgather
// (57->46us, FETCH 147->76MB via partition-local L2 reuse) + R8/R9's
// EPB=8192 partition (R10's EPB=4096 doubled per-block overhead: 2x LDS
// init + 2x global reservation atomics -> ~50us; 8192 was ~28us).
// Pipeline: memset(3KB) -> partition -> convertB -> sortgather.

#define GC_D 64
#define PBITS 8
#define PSIZE 256     // nodes per partition
#define SCAP 4096     // stream slots per partition (mean 3197, +16 sigma)
#define EPB 8192      // edges per block in partition pass (153 blocks)
#define MAXPART 512
#define GC_CAP 64     // fallback-A bucket capacity

// ---------------- main-path kernels ----------------

__global__ __launch_bounds__(512) void partition_kernel(
        const int* __restrict__ src,
        const int* __restrict__ dst,
        int* __restrict__ curA,                 // [nPart] cursors (dst-keyed)
        int* __restrict__ curB,                 // [nPart] cursors (src-keyed)
        int* __restrict__ streamA,              // [nPart*SCAP] s | (d&255)<<17
        unsigned char* __restrict__ streamB,    // [nPart*SCAP] s&255
        int e, int nPart) {
    __shared__ int histA[MAXPART], histB[MAXPART], baseA[MAXPART], baseB[MAXPART];
    __shared__ int lcurA[MAXPART], lcurB[MAXPART];
    int t = threadIdx.x;
    for (int i = t; i < nPart; i += 512) {
        histA[i] = 0; histB[i] = 0; lcurA[i] = 0; lcurB[i] = 0;
    }
    __syncthreads();
    int lo = blockIdx.x * EPB;
    int hi = min(lo + EPB, e);
    for (int i = lo + t; i < hi; i += 512) {
        int s = src[i], d = dst[i];
        atomicAdd(&histA[d >> PBITS], 1);
        atomicAdd(&histB[s >> PBITS], 1);
    }
    __syncthreads();
    for (int i = t; i < nPart; i += 512) {
        int hA = histA[i];
        baseA[i] = hA ? atomicAdd(&curA[i], hA) : 0;
        int hB = histB[i];
        baseB[i] = hB ? atomicAdd(&curB[i], hB) : 0;
    }
    __syncthreads();
    for (int i = lo + t; i < hi; i += 512) {
        int s = src[i], d = dst[i];
        int pA = d >> PBITS;
        int posA = baseA[pA] + atomicAdd(&lcurA[pA], 1);
        if (posA < SCAP) streamA[pA * SCAP + posA] = s | ((d & 255) << 17);
        int pB = s >> PBITS;
        int posB = baseB[pB] + atomicAdd(&lcurB[pB], 1);
        if (posB < SCAP) streamB[pB * SCAP + posB] = (unsigned char)(s & 255);
    }
}

// One block per partition: outdeg hist from streamB, then premultiplied bf16
// convert of this partition's 256 rows. featb row n = zeros (pad target).
__global__ __launch_bounds__(512) void convertB_kernel(
        const int* __restrict__ curB,
        const unsigned char* __restrict__ streamB,
        const float* __restrict__ feat,
        unsigned short* __restrict__ featb,
        int n) {
    __shared__ int lodeg[PSIZE];
    int p = blockIdx.x, t = threadIdx.x;
    if (t < PSIZE) lodeg[t] = 0;
    __syncthreads();
    int cB = min(curB[p], SCAP);
    const unsigned char* sB = streamB + (size_t)p * SCAP;
    for (int i = t; i < cB; i += 512) atomicAdd(&lodeg[sB[i]], 1);
    __syncthreads();
    int wave = t >> 6, lane = t & 63;
    int g = p * PSIZE;
    for (int r = wave; r < PSIZE; r += 8) {
        int node = g + r;
        if (node >= n) break;
        float nl = rsqrtf(fmaxf((float)lodeg[r], 1.0f) + 1.0f);
        float v = feat[(size_t)node * GC_D + lane] * nl;
        unsigned bb = __float_as_uint(v);
        bb = (bb + 0x7FFFu + ((bb >> 16) & 1u)) >> 16;   // RNE to bf16
        featb[(size_t)node * GC_D + lane] = (unsigned short)bb;
    }
    if (p == 0 && t < GC_D) featb[(size_t)n * GC_D + t] = 0;
}

// One 1024-thread block per partition. Drain streamA into LDS, LDS counting
// sort into lperm, then 16 waves gather 2 nodes at a time (r, r+16) with 16
// independent featb loads in flight per wave.
__global__ __launch_bounds__(1024) void sortgather_kernel(
        const int* __restrict__ curA,
        const int* __restrict__ streamA,
        const float* __restrict__ feat,
        const unsigned short* __restrict__ featb,
        float* __restrict__ out,
        int n) {
    __shared__ int sAl[SCAP];       // 16 KB staged stream
    __shared__ int lperm[SCAP];     // 16 KB sorted src ids
    __shared__ int lcnt[PSIZE], loff[PSIZE], lcur[PSIZE];
    int p = blockIdx.x, t = threadIdx.x;
    if (t < PSIZE) lcnt[t] = 0;
    __syncthreads();
    int cA = min(curA[p], SCAP);
    const int* sA = streamA + (size_t)p * SCAP;
    for (int i = t; i < cA; i += 1024) {
        int v = sA[i];
        sAl[i] = v;
        atomicAdd(&lcnt[(v >> 17) & 255], 1);
    }
    __syncthreads();
    // exclusive scan of the 256 bins (Hillis-Steele on first 256 threads)
    if (t < PSIZE) loff[t] = lcnt[t];
    __syncthreads();
    for (int off = 1; off < PSIZE; off <<= 1) {
        int a = (t < PSIZE && t >= off) ? loff[t - off] : 0;
        __syncthreads();
        if (t < PSIZE) loff[t] += a;
        __syncthreads();
    }
    if (t < PSIZE) { loff[t] -= lcnt[t]; lcur[t] = 0; }   // exclusive
    __syncthreads();
    for (int i = t; i < cA; i += 1024) {
        int v = sAl[i];
        int bin = (v >> 17) & 255;
        int pos = loff[bin] + atomicAdd(&lcur[bin], 1);
        lperm[pos] = v & 0x1FFFF;
    }
    __syncthreads();
    // gather: wave w handles node pairs (w, w+16), (w+32, w+48), ...
    int wave = t >> 6, lane = t & 63;
    int half = lane >> 5;      // 0: even edges, 1: odd edges
    int c = lane & 31;         // feature-pair index
    int g = p * PSIZE;
    for (int rr = wave; rr < PSIZE; rr += 32) {
        int rA = rr, rB = rr + 16;
        int nodeA = g + rA, nodeB = g + rB;
        int degA = lcnt[rA], degB = lcnt[rB];
        int offA = loff[rA], offB = loff[rB];
        int mA = min(degA, 64), mB = min(degB, 64);
        int s_lA = (lane < mA) ? lperm[offA + lane] : n;
        int s_lB = (lane < mB) ? lperm[offB + lane] : n;
        float a0 = 0.f, a1 = 0.f, b0 = 0.f, b1 = 0.f;
        int mA16 = (mA + 15) & ~15, mB16 = (mB + 15) & ~15;
        int mx = mA16 > mB16 ? mA16 : mB16;
        for (int j = 0; j < mx; j += 16) {
            unsigned uA[8], uB[8];
#pragma unroll
            for (int k = 0; k < 8; ++k) {
                int s = __shfl(s_lA, j + 2 * k + half);
                uA[k] = *(const unsigned*)(featb + (size_t)s * GC_D + 2 * c);
            }
#pragma unroll
            for (int k = 0; k < 8; ++k) {
                int s = __shfl(s_lB, j + 2 * k + half);
                uB[k] = *(const unsigned*)(featb + (size_t)s * GC_D + 2 * c);
            }
#pragma unroll
            for (int k = 0; k < 8; ++k) {
                a0 += __uint_as_float(uA[k] << 16);
                a1 += __uint_as_float(uA[k] & 0xFFFF0000u);
            }
#pragma unroll
            for (int k = 0; k < 8; ++k) {
                b0 += __uint_as_float(uB[k] << 16);
                b1 += __uint_as_float(uB[k] & 0xFFFF0000u);
            }
        }
        // rare tails (deg > 64): sequential batches, statistically ~never
        for (int base = 64; base < degA; base += 64) {
            int m = min(degA - base, 64);
            int s_l = (lane < m) ? lperm[offA + base + lane] : n;
            int m16 = (m + 15) & ~15;
            for (int j = 0; j < m16; j += 16) {
#pragma unroll
                for (int k = 0; k < 8; ++k) {
                    int s = __shfl(s_l, j + 2 * k + half);
                    unsigned u = *(const unsigned*)(featb + (size_t)s * GC_D + 2 * c);
                    a0 += __uint_as_float(u << 16);
                    a1 += __uint_as_float(u & 0xFFFF0000u);
                }
            }
        }
        for (int base = 64; base < degB; base += 64) {
            int m = min(degB - base, 64);
            int s_l = (lane < m) ? lperm[offB + base + lane] : n;
            int m16 = (m + 15) & ~15;
            for (int j = 0; j < m16; j += 16) {
#pragma unroll
                for (int k = 0; k < 8; ++k) {
                    int s = __shfl(s_l, j + 2 * k + half);
                    unsigned u = *(const unsigned*)(featb + (size_t)s * GC_D + 2 * c);
                    b0 += __uint_as_float(u << 16);
                    b1 += __uint_as_float(u & 0xFFFF0000u);
                }
            }
        }
        a0 += __shfl_xor(a0, 32);
        a1 += __shfl_xor(a1, 32);
        b0 += __shfl_xor(b0, 32);
        b1 += __shfl_xor(b1, 32);
        if (half == 0) {
            if (nodeA < n) {
                float nr = rsqrtf(fmaxf((float)degA, 1.0f) + 1.0f);
                const float2 self = *(const float2*)(feat + (size_t)nodeA * GC_D + 2 * c);
                float2 rv;
                rv.x = (self.x + a0) * nr;
                rv.y = (self.y + a1) * nr;
                *(float2*)(out + (size_t)nodeA * GC_D + 2 * c) = rv;
            }
            if (nodeB < n) {
                float nr = rsqrtf(fmaxf((float)degB, 1.0f) + 1.0f);
                const float2 self = *(const float2*)(feat + (size_t)nodeB * GC_D + 2 * c);
                float2 rv;
                rv.x = (self.x + b0) * nr;
                rv.y = (self.y + b1) * nr;
                *(float2*)(out + (size_t)nodeB * GC_D + 2 * c) = rv;
            }
        }
    }
}

// ---------------- fallback A (atomic-bucket path, R4-style) ----------------

__global__ void zero_int_kernel(int* __restrict__ p, int n) {
    int i = blockIdx.x * blockDim.x + threadIdx.x;
    if (i < n) p[i] = 0;
}

__global__ void bucket_hist_kernel(const int* __restrict__ src,
                                   const int* __restrict__ dst,
                                   int* __restrict__ cnt,
                                   int* __restrict__ outdeg,
                                   int* __restrict__ bucket,
                                   int e) {
    int i = blockIdx.x * blockDim.x + threadIdx.x;
    if (i < e) {
        int s = src[i];
        int d = dst[i];
        atomicAdd(&outdeg[s], 1);
        int pos = atomicAdd(&cnt[d], 1);
        if (pos < GC_CAP) bucket[d * GC_CAP + pos] = s;
    }
}

__global__ void convert_kernel(const float* __restrict__ feat,
                               const int* __restrict__ outdeg,
                               unsigned short* __restrict__ featb,
                               int n) {
    int i = blockIdx.x * blockDim.x + threadIdx.x;
    int total = (n + 1) * GC_D;
    if (i >= total) return;
    int row = i >> 6;
    if (row >= n) { featb[i] = 0; return; }
    float nl = rsqrtf(fmaxf((float)outdeg[row], 1.0f) + 1.0f);
    unsigned b = __float_as_uint(feat[i] * nl);
    b = (b + 0x7FFFu + ((b >> 16) & 1u)) >> 16;
    featb[i] = (unsigned short)b;
}

__global__ __launch_bounds__(256) void gather_bf16_kernel(
        const float* __restrict__ feat,
        const unsigned short* __restrict__ featb,
        const int* __restrict__ bucket,
        const int* __restrict__ cnt,
        float* __restrict__ out,
        int n) {
    int wid = (blockIdx.x * blockDim.x + threadIdx.x) >> 6;
    int lane = threadIdx.x & 63;
    if (wid >= n) return;
    int deg = cnt[wid];
    int s_raw = bucket[wid * GC_CAP + lane];
    int m = min(deg, GC_CAP);
    int s_l = (lane < m) ? s_raw : n;
    int half = lane >> 5;
    int c = lane & 31;
    float acc0 = 0.0f, acc1 = 0.0f;
    int m16 = (m + 15) & ~15;
    for (int j = 0; j < m16; j += 16) {
#pragma unroll
        for (int k = 0; k < 8; ++k) {
            int s = __shfl(s_l, j + 2 * k + half);
            unsigned u = *(const unsigned*)(featb + (size_t)s * GC_D + 2 * c);
            acc0 += __uint_as_float(u << 16);
            acc1 += __uint_as_float(u & 0xFFFF0000u);
        }
    }
    acc0 += __shfl_xor(acc0, 32);
    acc1 += __shfl_xor(acc1, 32);
    if (half == 0) {
        float nr = rsqrtf(fmaxf((float)deg, 1.0f) + 1.0f);
        const float2 self = *(const float2*)(feat + (size_t)wid * GC_D + 2 * c);
        float2 r;
        r.x = (self.x + acc0) * nr;
        r.y = (self.y + acc1) * nr;
        *(float2*)(out + (size_t)wid * GC_D + 2 * c) = r;
    }
}

// ---------------- launch ----------------

extern "C" void kernel_launch(void* const* d_in, const int* in_sizes, int n_in,
                              void* d_out, int out_size, void* d_ws, size_t ws_size,
                              hipStream_t stream) {
    const float* feat = (const float*)d_in[0];
    const int*   src  = (const int*)d_in[1];
    const int*   dst  = (const int*)d_in[2];
    float* out = (float*)d_out;

    const int n = in_sizes[0] / GC_D;   // 100000
    const int e = in_sizes[1];          // 1250000
    const int nPart = (n + PSIZE - 1) >> PBITS;   // 391

    // Main ws layout (int units): curA[nPart] curB[nPart] pad32 ->
    //   streamA[nPart*SCAP] -> featb[(n+1)*64 u16] -> streamB[nPart*SCAP u8]
    size_t featb_ints = ((size_t)(n + 1) * GC_D + 1) / 2;
    size_t o = 2 * (size_t)nPart;
    o = (o + 31) & ~(size_t)31;          // 128B-align streamA (and featb below)
    size_t streamA_o = o;  o += (size_t)nPart * SCAP;
    size_t featb_o = o;    o += featb_ints;
    size_t need_main = o * sizeof(int) + (size_t)nPart * SCAP;   // + streamB u8

    size_t featb_bytes = (size_t)(n + 1) * GC_D * sizeof(unsigned short);
    size_t need_bf16 = ((size_t)2 * n + (size_t)n * GC_CAP) * sizeof(int) + featb_bytes;

    bool main_ok = (ws_size >= need_main) && nPart <= MAXPART && n <= 131071;

    if (main_ok) {
        int* ws = (int*)d_ws;
        int* curA = ws;
        int* curB = ws + nPart;
        int* streamA = ws + streamA_o;
        unsigned short* featb = (unsigned short*)(ws + featb_o);
        unsigned char* streamB = (unsigned char*)(ws + o);

        hipMemsetAsync(curA, 0, 2 * (size_t)nPart * sizeof(int), stream);
        partition_kernel<<<(e + EPB - 1) / EPB, 512, 0, stream>>>(
            src, dst, curA, curB, streamA, streamB, e, nPart);
        convertB_kernel<<<nPart, 512, 0, stream>>>(curB, streamB, feat, featb, n);
        sortgather_kernel<<<nPart, 1024, 0, stream>>>(curA, streamA, feat, featb,
                                                      out, n);
    } else if (ws_size >= need_bf16) {
        int* cnt    = (int*)d_ws;
        int* outdeg = cnt + n;
        int* bucket = outdeg + n;
        unsigned short* featb = (unsigned short*)(bucket + (size_t)n * GC_CAP);

        zero_int_kernel<<<(2 * n + 255) / 256, 256, 0, stream>>>(cnt, 2 * n);
        bucket_hist_kernel<<<(e + 255) / 256, 256, 0, stream>>>(src, dst, cnt,
                                                                outdeg, bucket, e);
        int totalc = (n + 1) * GC_D;
        convert_kernel<<<(totalc + 255) / 256, 256, 0, stream>>>(feat, outdeg,
                                                                 featb, n);
        long long total = (long long)n * GC_D;
        gather_bf16_kernel<<<(int)((total + 255) / 256), 256, 0, stream>>>(
            feat, featb, bucket, cnt, out, n);
    }
}

// Round 13
// 154.032 us; speedup vs baseline: 1.1323x; 1.1026x over previous
//
#include <hip/hip_runtime.h>

// GraphConv (DGL norm='both', implicit self-loop), N=100000, D=64, E=1250000.
// R12: R9's 1-node-per-wave gather restored (2-node pipeline was a measured
// ~5us regression - max(mA,mB) padding + compiler already overlaps r-iters).
// Structural fix: nPart 391 -> 511 (PSIZE 196, compile-time magic-div) so
// sortgather's 1024-thread blocks land ~exactly 2 per CU - removes the
// 2-vs-1 block/CU imbalance where 135 loaded CUs set the finish line.
// Pipeline: memset(4KB) -> partition -> convertB -> sortgather.

#define GC_D 64
#define PSIZE 196     // nodes per partition: ceil(100000/511); 511 ~ 2*256 CUs
#define SCAP 3072     // stream slots per partition (mean 2450, +12 sigma)
#define EPB 8192      // edges per block in partition pass (153 blocks)
#define MAXPART 512
#define GC_CAP 64     // fallback-A bucket capacity

// ---------------- main-path kernels ----------------

__global__ __launch_bounds__(512) void partition_kernel(
        const int* __restrict__ src,
        const int* __restrict__ dst,
        int* __restrict__ curA,                 // [nPart] cursors (dst-keyed)
        int* __restrict__ curB,                 // [nPart] cursors (src-keyed)
        int* __restrict__ streamA,              // [nPart*SCAP] s | (d%PSIZE)<<17
        unsigned char* __restrict__ streamB,    // [nPart*SCAP] s%PSIZE
        int e, int nPart) {
    __shared__ int histA[MAXPART], histB[MAXPART], baseA[MAXPART], baseB[MAXPART];
    __shared__ int lcurA[MAXPART], lcurB[MAXPART];
    int t = threadIdx.x;
    for (int i = t; i < nPart; i += 512) {
        histA[i] = 0; histB[i] = 0; lcurA[i] = 0; lcurB[i] = 0;
    }
    __syncthreads();
    int lo = blockIdx.x * EPB;
    int hi = min(lo + EPB, e);
    for (int i = lo + t; i < hi; i += 512) {
        int s = src[i], d = dst[i];
        atomicAdd(&histA[d / PSIZE], 1);
        atomicAdd(&histB[s / PSIZE], 1);
    }
    __syncthreads();
    for (int i = t; i < nPart; i += 512) {
        int hA = histA[i];
        baseA[i] = hA ? atomicAdd(&curA[i], hA) : 0;
        int hB = histB[i];
        baseB[i] = hB ? atomicAdd(&curB[i], hB) : 0;
    }
    __syncthreads();
    for (int i = lo + t; i < hi; i += 512) {
        int s = src[i], d = dst[i];
        int pA = d / PSIZE;
        int posA = baseA[pA] + atomicAdd(&lcurA[pA], 1);
        if (posA < SCAP) streamA[pA * SCAP + posA] = s | ((d - pA * PSIZE) << 17);
        int pB = s / PSIZE;
        int posB = baseB[pB] + atomicAdd(&lcurB[pB], 1);
        if (posB < SCAP) streamB[pB * SCAP + posB] = (unsigned char)(s - pB * PSIZE);
    }
}

// One block per partition: outdeg hist from streamB, then premultiplied bf16
// convert of this partition's PSIZE rows. featb row n = zeros (pad target).
__global__ __launch_bounds__(512) void convertB_kernel(
        const int* __restrict__ curB,
        const unsigned char* __restrict__ streamB,
        const float* __restrict__ feat,
        unsigned short* __restrict__ featb,
        int n) {
    __shared__ int lodeg[256];
    int p = blockIdx.x, t = threadIdx.x;
    if (t < 256) lodeg[t] = 0;
    __syncthreads();
    int cB = min(curB[p], SCAP);
    const unsigned char* sB = streamB + (size_t)p * SCAP;
    for (int i = t; i < cB; i += 512) atomicAdd(&lodeg[sB[i]], 1);
    __syncthreads();
    int wave = t >> 6, lane = t & 63;
    int g = p * PSIZE;
    for (int r = wave; r < PSIZE; r += 8) {
        int node = g + r;
        if (node >= n) break;
        float nl = rsqrtf(fmaxf((float)lodeg[r], 1.0f) + 1.0f);
        float v = feat[(size_t)node * GC_D + lane] * nl;
        unsigned bb = __float_as_uint(v);
        bb = (bb + 0x7FFFu + ((bb >> 16) & 1u)) >> 16;   // RNE to bf16
        featb[(size_t)node * GC_D + lane] = (unsigned short)bb;
    }
    if (p == 0 && t < GC_D) featb[(size_t)n * GC_D + t] = 0;
}

// One 1024-thread block per partition (~2 blocks/CU, balanced). Drain streamA
// into LDS, LDS counting sort into lperm, 16 waves gather one node at a time
// (R9's proven pattern: compiler overlaps independent r-iterations).
__global__ __launch_bounds__(1024) void sortgather_kernel(
        const int* __restrict__ curA,
        const int* __restrict__ streamA,
        const float* __restrict__ feat,
        const unsigned short* __restrict__ featb,
        float* __restrict__ out,
        int n) {
    __shared__ int sAl[SCAP];       // 12 KB staged stream
    __shared__ int lperm[SCAP];     // 12 KB sorted src ids
    __shared__ int lcnt[256], loff[256], lcur[256];
    int p = blockIdx.x, t = threadIdx.x;
    if (t < 256) lcnt[t] = 0;
    __syncthreads();
    int cA = min(curA[p], SCAP);
    const int* sA = streamA + (size_t)p * SCAP;
    for (int i = t; i < cA; i += 1024) {
        int v = sA[i];
        sAl[i] = v;
        atomicAdd(&lcnt[(v >> 17) & 255], 1);
    }
    __syncthreads();
    // exclusive scan of 256 bins (Hillis-Steele on first 256 threads)
    if (t < 256) loff[t] = lcnt[t];
    __syncthreads();
    for (int off = 1; off < 256; off <<= 1) {
        int a = (t < 256 && t >= off) ? loff[t - off] : 0;
        __syncthreads();
        if (t < 256) loff[t] += a;
        __syncthreads();
    }
    if (t < 256) { loff[t] -= lcnt[t]; lcur[t] = 0; }   // exclusive
    __syncthreads();
    for (int i = t; i < cA; i += 1024) {
        int v = sAl[i];
        int bin = (v >> 17) & 255;
        int pos = loff[bin] + atomicAdd(&lcur[bin], 1);
        lperm[pos] = v & 0x1FFFF;
    }
    __syncthreads();
    // gather: wave w handles nodes w, w+16, ...
    int wave = t >> 6, lane = t & 63;
    int half = lane >> 5;      // 0: even edges, 1: odd edges
    int c = lane & 31;         // feature-pair index
    int g = p * PSIZE;
    for (int r = wave; r < PSIZE; r += 16) {
        int node = g + r;
        if (node >= n) break;
        int deg = lcnt[r];
        int off = loff[r];
        float acc0 = 0.0f, acc1 = 0.0f;
        for (int base = 0; base < deg; base += 64) {
            int m = min(deg - base, 64);
            int s_l = (lane < m) ? lperm[off + base + lane] : n;
            int m16 = (m + 15) & ~15;
            for (int j = 0; j < m16; j += 16) {
#pragma unroll
                for (int k = 0; k < 8; ++k) {
                    int s = __shfl(s_l, j + 2 * k + half);
                    unsigned u = *(const unsigned*)(featb + (size_t)s * GC_D + 2 * c);
                    acc0 += __uint_as_float(u << 16);
                    acc1 += __uint_as_float(u & 0xFFFF0000u);
                }
            }
        }
        acc0 += __shfl_xor(acc0, 32);
        acc1 += __shfl_xor(acc1, 32);
        if (half == 0) {
            float nr = rsqrtf(fmaxf((float)deg, 1.0f) + 1.0f);
            const float2 self = *(const float2*)(feat + (size_t)node * GC_D + 2 * c);
            float2 rr;
            rr.x = (self.x + acc0) * nr;
            rr.y = (self.y + acc1) * nr;
            *(float2*)(out + (size_t)node * GC_D + 2 * c) = rr;
        }
    }
}

// ---------------- fallback A (atomic-bucket path, R4-style) ----------------

__global__ void zero_int_kernel(int* __restrict__ p, int n) {
    int i = blockIdx.x * blockDim.x + threadIdx.x;
    if (i < n) p[i] = 0;
}

__global__ void bucket_hist_kernel(const int* __restrict__ src,
                                   const int* __restrict__ dst,
                                   int* __restrict__ cnt,
                                   int* __restrict__ outdeg,
                                   int* __restrict__ bucket,
                                   int e) {
    int i = blockIdx.x * blockDim.x + threadIdx.x;
    if (i < e) {
        int s = src[i];
        int d = dst[i];
        atomicAdd(&outdeg[s], 1);
        int pos = atomicAdd(&cnt[d], 1);
        if (pos < GC_CAP) bucket[d * GC_CAP + pos] = s;
    }
}

__global__ void convert_kernel(const float* __restrict__ feat,
                               const int* __restrict__ outdeg,
                               unsigned short* __restrict__ featb,
                               int n) {
    int i = blockIdx.x * blockDim.x + threadIdx.x;
    int total = (n + 1) * GC_D;
    if (i >= total) return;
    int row = i >> 6;
    if (row >= n) { featb[i] = 0; return; }
    float nl = rsqrtf(fmaxf((float)outdeg[row], 1.0f) + 1.0f);
    unsigned b = __float_as_uint(feat[i] * nl);
    b = (b + 0x7FFFu + ((b >> 16) & 1u)) >> 16;
    featb[i] = (unsigned short)b;
}

__global__ __launch_bounds__(256) void gather_bf16_kernel(
        const float* __restrict__ feat,
        const unsigned short* __restrict__ featb,
        const int* __restrict__ bucket,
        const int* __restrict__ cnt,
        float* __restrict__ out,
        int n) {
    int wid = (blockIdx.x * blockDim.x + threadIdx.x) >> 6;
    int lane = threadIdx.x & 63;
    if (wid >= n) return;
    int deg = cnt[wid];
    int s_raw = bucket[wid * GC_CAP + lane];
    int m = min(deg, GC_CAP);
    int s_l = (lane < m) ? s_raw : n;
    int half = lane >> 5;
    int c = lane & 31;
    float acc0 = 0.0f, acc1 = 0.0f;
    int m16 = (m + 15) & ~15;
    for (int j = 0; j < m16; j += 16) {
#pragma unroll
        for (int k = 0; k < 8; ++k) {
            int s = __shfl(s_l, j + 2 * k + half);
            unsigned u = *(const unsigned*)(featb + (size_t)s * GC_D + 2 * c);
            acc0 += __uint_as_float(u << 16);
            acc1 += __uint_as_float(u & 0xFFFF0000u);
        }
    }
    acc0 += __shfl_xor(acc0, 32);
    acc1 += __shfl_xor(acc1, 32);
    if (half == 0) {
        float nr = rsqrtf(fmaxf((float)deg, 1.0f) + 1.0f);
        const float2 self = *(const float2*)(feat + (size_t)wid * GC_D + 2 * c);
        float2 r;
        r.x = (self.x + acc0) * nr;
        r.y = (self.y + acc1) * nr;
        *(float2*)(out + (size_t)wid * GC_D + 2 * c) = r;
    }
}

// ---------------- launch ----------------

extern "C" void kernel_launch(void* const* d_in, const int* in_sizes, int n_in,
                              void* d_out, int out_size, void* d_ws, size_t ws_size,
                              hipStream_t stream) {
    const float* feat = (const float*)d_in[0];
    const int*   src  = (const int*)d_in[1];
    const int*   dst  = (const int*)d_in[2];
    float* out = (float*)d_out;

    const int n = in_sizes[0] / GC_D;   // 100000
    const int e = in_sizes[1];          // 1250000
    const int nPart = (n + PSIZE - 1) / PSIZE;    // 511 for n=100000

    // Main ws layout (int units): curA[nPart] curB[nPart] pad32 ->
    //   streamA[nPart*SCAP] -> featb[(n+1)*64 u16] -> streamB[nPart*SCAP u8]
    size_t featb_ints = ((size_t)(n + 1) * GC_D + 1) / 2;
    size_t o = 2 * (size_t)nPart;
    o = (o + 31) & ~(size_t)31;          // 128B-align streamA (and featb below)
    size_t streamA_o = o;  o += (size_t)nPart * SCAP;
    size_t featb_o = o;    o += featb_ints;
    size_t need_main = o * sizeof(int) + (size_t)nPart * SCAP;   // + streamB u8

    size_t featb_bytes = (size_t)(n + 1) * GC_D * sizeof(unsigned short);
    size_t need_bf16 = ((size_t)2 * n + (size_t)n * GC_CAP) * sizeof(int) + featb_bytes;

    bool main_ok = (ws_size >= need_main) && nPart <= MAXPART && n <= 131071;

    if (main_ok) {
        int* ws = (int*)d_ws;
        int* curA = ws;
        int* curB = ws + nPart;
        int* streamA = ws + streamA_o;
        unsigned short* featb = (unsigned short*)(ws + featb_o);
        unsigned char* streamB = (unsigned char*)(ws + o);

        hipMemsetAsync(curA, 0, 2 * (size_t)nPart * sizeof(int), stream);
        partition_kernel<<<(e + EPB - 1) / EPB, 512, 0, stream>>>(
            src, dst, curA, curB, streamA, streamB, e, nPart);
        convertB_kernel<<<nPart, 512, 0, stream>>>(curB, streamB, feat, featb, n);
        sortgather_kernel<<<nPart, 1024, 0, stream>>>(curA, streamA, feat, featb,
                                                      out, n);
    } else if (ws_size >= need_bf16) {
        int* cnt    = (int*)d_ws;
        int* outdeg = cnt + n;
        int* bucket = outdeg + n;
        unsigned short* featb = (unsigned short*)(bucket + (size_t)n * GC_CAP);

        zero_int_kernel<<<(2 * n + 255) / 256, 256, 0, stream>>>(cnt, 2 * n);
        bucket_hist_kernel<<<(e + 255) / 256, 256, 0, stream>>>(src, dst, cnt,
                                                                outdeg, bucket, e);
        int totalc = (n + 1) * GC_D;
        convert_kernel<<<(totalc + 255) / 256, 256, 0, stream>>>(feat, outdeg,
                                                                 featb, n);
        long long total = (long long)n * GC_D;
        gather_bf16_kernel<<<(int)((total + 255) / 256), 256, 0, stream>>>(
            feat, featb, bucket, cnt, out, n);
    }
}